// Round 2
// baseline (239.559 us; speedup 1.0000x reference)
//
#include <hip/hip_runtime.h>
#include <hip/hip_bf16.h>
#include <math.h>

typedef __bf16 bf16;
typedef __bf16 bf16x8 __attribute__((ext_vector_type(8)));
typedef __bf16 bf16x4 __attribute__((ext_vector_type(4)));
typedef float f32x4 __attribute__((ext_vector_type(4)));

#define S_ 4096
#define D_ 1024
#define H_ 16
#define HD_ 64
#define N3_ 3072
#define NSPLIT 4

// async global->LDS 16B (m97 pattern)
typedef const __attribute__((address_space(1))) void* gas1_t;
typedef __attribute__((address_space(3))) void* las3_t;
static __device__ __forceinline__ void g2l16(const void* g, void* l) {
  __builtin_amdgcn_global_load_lds((gas1_t)g, (las3_t)l, 16, 0, 0);
}

// ---------------- fused prep: cvt x -> bf16, transpose both weights ----------------
// grid: [0,4096) cvt | [4096,7168) w_qkv transpose | [7168,8192) w_proj transpose
__global__ __launch_bounds__(256) void prep_kernel(const float* __restrict__ x,
                                                   bf16* __restrict__ xb,
                                                   const float* __restrict__ w_qkv,
                                                   bf16* __restrict__ wqkvT,
                                                   const float* __restrict__ w_proj,
                                                   bf16* __restrict__ wprojT) {
  __shared__ float t[32][33];
  const int b = blockIdx.x;
  if (b < 4096) {
    int i = (b * 256 + threadIdx.x) * 4;
    float4 v = *(const float4*)(x + i);
    bf16x4 o;
    o.x = (bf16)v.x; o.y = (bf16)v.y; o.z = (bf16)v.z; o.w = (bf16)v.w;
    *(bf16x4*)(xb + i) = o;
    return;
  }
  const float* in; bf16* outp; int ldin, bx, by;
  if (b < 7168) { int b2 = b - 4096; in = w_qkv;  outp = wqkvT;  ldin = N3_; bx = (b2 % 96) * 32; by = (b2 / 96) * 32; }
  else          { int b3 = b - 7168; in = w_proj; outp = wprojT; ldin = D_;  bx = (b3 % 32) * 32; by = (b3 / 32) * 32; }
  const int tx = threadIdx.x & 31, ty = threadIdx.x >> 5;
#pragma unroll
  for (int i = 0; i < 4; ++i)
    t[ty + i * 8][tx] = in[(size_t)(by + ty + i * 8) * ldin + bx + tx];
  __syncthreads();
#pragma unroll
  for (int i = 0; i < 4; ++i)
    outp[(size_t)(bx + ty + i * 8) * D_ + by + tx] = (bf16)t[tx][ty + i * 8];
}

// ---------------- bf16 GEMM (m97 pattern): C = A * Bt^T + bias ----------------
template <int BN>
__global__ __launch_bounds__(256) void gemm_bt(const bf16* __restrict__ A,
                                               const bf16* __restrict__ Bt,
                                               const float* __restrict__ bias,
                                               bf16* __restrict__ outb,
                                               float* __restrict__ outf,
                                               bf16* __restrict__ vTout,
                                               int M, int N, int K,
                                               int qlim, float qscale) {
  constexpr int NT = BN / 32;  // n-tiles per wave
  __shared__ bf16 sA[128 * 32];
  __shared__ bf16 sB[BN * 32];
  const int tid = threadIdx.x;
  const int wave = tid >> 6, lane = tid & 63;
  const int col = lane & 15, quad = lane >> 4;
  const int wm = (wave & 1) * 64, wn = (wave >> 1) * (BN / 2);
  const long bm = (long)blockIdx.x * 128, bn = (long)blockIdx.y * BN;
  const int srow = tid >> 2;        // 0..63
  const int soff = (tid & 3) * 8;   // elem in 32-elem row

  f32x4 acc[4][NT] = {};

  for (int kb = 0; kb < K; kb += 32) {
    __syncthreads();
    g2l16(A + (bm + srow) * (long)K + kb + soff,      &sA[tid * 8]);
    g2l16(A + (bm + 64 + srow) * (long)K + kb + soff, &sA[2048 + tid * 8]);
#pragma unroll
    for (int i = 0; i < BN / 64; ++i)
      g2l16(Bt + (bn + i * 64 + srow) * (long)K + kb + soff, &sB[i * 2048 + tid * 8]);
    __syncthreads();

    bf16x8 af[4], bfr[NT];
#pragma unroll
    for (int t = 0; t < 4; ++t)
      af[t] = *(const bf16x8*)(&sA[(wm + t * 16 + col) * 32 + quad * 8]);
#pragma unroll
    for (int t = 0; t < NT; ++t)
      bfr[t] = *(const bf16x8*)(&sB[(wn + t * 16 + col) * 32 + quad * 8]);
#pragma unroll
    for (int mt = 0; mt < 4; ++mt)
#pragma unroll
      for (int nt = 0; nt < NT; ++nt)
        acc[mt][nt] = __builtin_amdgcn_mfma_f32_16x16x32_bf16(af[mt], bfr[nt], acc[mt][nt], 0, 0, 0);
  }

#pragma unroll
  for (int mt = 0; mt < 4; ++mt) {
#pragma unroll
    for (int nt = 0; nt < NT; ++nt) {
      long gn = bn + wn + nt * 16 + col;
      float bv = bias ? bias[gn] : 0.f;
      if (vTout && gn >= 2 * D_) {  // V column -> transposed store
        bf16x4 vv;
        long gm0 = bm + wm + mt * 16 + quad * 4;
#pragma unroll
        for (int i = 0; i < 4; ++i) vv[i] = (bf16)(acc[mt][nt][i] + bv);
        *(bf16x4*)(&vTout[(gn - 2 * D_) * (long)S_ + gm0]) = vv;
      } else {
        float sc = (gn < qlim) ? qscale : 1.0f;
#pragma unroll
        for (int i = 0; i < 4; ++i) {
          long gm = bm + wm + mt * 16 + quad * 4 + i;
          float v = (acc[mt][nt][i] + bv) * sc;
          if (outf) outf[gm * N + gn] = v;
          else      outb[gm * N + gn] = (bf16)v;
        }
      }
    }
  }
}

// ---------------- causal flash attention, contiguous exact K-split ----------------
// grid (H, 16, 4), block 256 = 4 waves; 256 q-rows/block (64/wave as FOUR 16-row
// subtiles sharing K/V fragment reads -- 2x arithmetic intensity per LDS read vs
// the 32-row/wave version); 64-key chunks, double-buffered XOR-swizzled LDS,
// global_load_lds staging with inverse-swizzled per-lane SOURCE addresses
// (m173 pattern: LDS dst linear base+lane*16, source pre-permuted so slot
// (row, x) holds global chunk x ^ swz_g(row) -- identical involution to the
// read side). ONE barrier per chunk; stage(j+1) issued before compute(j).
// Q pre-scaled by 0.125*log2e so p = exp2(s). l via MFMA against ones.
// Contiguous split: niter = 4(qb+1) divisible by 4 -> all splits equal length,
// never empty. No-max softmax partials combine by pure addition -- exact.
__device__ __forceinline__ int swz_g(int row) {
  return (row & 3) | ((((row >> 2) ^ (row >> 3)) & 1) << 2);
}

__global__ __launch_bounds__(256) void attn_kernel(const bf16* __restrict__ qkv,
                                                   const bf16* __restrict__ vT,
                                                   bf16* __restrict__ Opart,
                                                   float* __restrict__ lws) {
  __shared__ bf16 sK[2][64 * 64];
  __shared__ bf16 sV[2][64 * 64];
  const int hh = blockIdx.x;
  const int qb = (int)(gridDim.y - 1 - blockIdx.y);  // heavy blocks dispatch first
  const int sp = blockIdx.z;
  const int tid = threadIdx.x;
  const int wave = tid >> 6, lane = tid & 63;
  const int col = lane & 15, quad = lane >> 4;
  const int qbase = qb * 256 + wave * 64;

  // Q fragments (B-operand layout) for the four 16-row subtiles
  const bf16* qp0 = qkv + (size_t)(qbase + col) * N3_ + hh * HD_;
  bf16x8 aq[4][2];
#pragma unroll
  for (int s2 = 0; s2 < 4; ++s2) {
    aq[s2][0] = *(const bf16x8*)(qp0 + (size_t)(16 * s2) * N3_ + quad * 8);
    aq[s2][1] = *(const bf16x8*)(qp0 + (size_t)(16 * s2) * N3_ + 32 + quad * 8);
  }

  bf16x8 ones;
#pragma unroll
  for (int j = 0; j < 8; ++j) ones[j] = (bf16)1.0f;

  f32x4 acc[4][4] = {};
  f32x4 acc_l[4] = {};

  const bf16* kgbase = qkv + D_ + hh * HD_;
  const bf16* vgbase = vT + (size_t)hh * HD_ * S_;
  const int krow = (col >> 2) * 8 + (col & 3);  // permuted K row (m = col)

  // --- global_load_lds staging: dst = wave_base + lane*16B (linear),
  // source chunk inverse-swizzled so LDS slot (row, x) holds chunk x^swz_g(row)
  const int lrow = lane >> 3, lc = lane & 7;
  const int row0 = wave * 16 + lrow;   // staged row, instr q=0
  const int row1 = row0 + 8;           // instr q=1
  const int c0 = lc ^ swz_g(row0);
  const int c1 = lc ^ swz_g(row1);
  const int dst0 = wave * 1024 + lane * 8;  // bf16 offset == wave_base + lane*16B
  const int dst1 = dst0 + 512;

  const int niter = 4 * (qb + 1);       // divisible by NSPLIT=4
  const int len = niter >> 2;
  const int it0 = sp * len;
  const int it1 = it0 + len;

  // prologue: stage chunk it0 into buf 0
  {
    const int kb2 = it0 * 64;
    g2l16(kgbase + (size_t)(kb2 + row0) * N3_ + c0 * 8, &sK[0][dst0]);
    g2l16(kgbase + (size_t)(kb2 + row1) * N3_ + c1 * 8, &sK[0][dst1]);
    g2l16(vgbase + (size_t)row0 * S_ + kb2 + c0 * 8, &sV[0][dst0]);
    g2l16(vgbase + (size_t)row1 * S_ + kb2 + c1 * 8, &sV[0][dst1]);
  }
  __syncthreads();

  int cur = 0;
  for (int j = it0; j < it1; ++j, cur ^= 1) {
    const int kb = j * 64;
    if (j + 1 < it1) {  // stage next chunk into the other buffer (async)
      const int kb2 = kb + 64;
      const int nb = cur ^ 1;
      g2l16(kgbase + (size_t)(kb2 + row0) * N3_ + c0 * 8, &sK[nb][dst0]);
      g2l16(kgbase + (size_t)(kb2 + row1) * N3_ + c1 * 8, &sK[nb][dst1]);
      g2l16(vgbase + (size_t)row0 * S_ + kb2 + c0 * 8, &sV[nb][dst0]);
      g2l16(vgbase + (size_t)row1 * S_ + kb2 + c1 * 8, &sV[nb][dst1]);
    }

    if (kb < qbase + 64) {  // wave has unmasked work in this chunk
      const bf16* kc = &sK[cur][0];
      const bf16* vc = &sV[cur][0];
      bf16x8 pfrag[4][2];

      __builtin_amdgcn_s_setprio(1);
      // --- S^T tiles: t = (chunk c = t>>1, half h = t&1); K-frags shared
      //     across all four q-subtiles; incremental exp2+pack per t keeps
      //     register pressure low (no st[4][4] array).
#pragma unroll
      for (int t = 0; t < 4; ++t) {
        const int row = (t >> 1) * 32 + (t & 1) * 4 + krow;
        const int pc = quad ^ swz_g(row);
        bf16x8 bk0 = *(const bf16x8*)(kc + row * 64 + pc * 8);
        bf16x8 bk1 = *(const bf16x8*)(kc + row * 64 + (pc ^ 4) * 8);
        f32x4 stt[4];
#pragma unroll
        for (int s2 = 0; s2 < 4; ++s2) {
          if (kb < qbase + 16 * s2 + 16) {  // subtile active (wave-uniform)
            f32x4 z = {};
            z = __builtin_amdgcn_mfma_f32_16x16x32_bf16(bk0, aq[s2][0], z, 0, 0, 0);
            stt[s2] = __builtin_amdgcn_mfma_f32_16x16x32_bf16(bk1, aq[s2][1], z, 0, 0, 0);
          }
        }
#pragma unroll
        for (int s2 = 0; s2 < 4; ++s2) {
          if (kb < qbase + 16 * s2 + 16) {
            const int rowbase = qbase + 16 * s2;
            float p[4];
            if (kb + 63 <= rowbase) {  // fully unmasked
#pragma unroll
              for (int r = 0; r < 4; ++r) p[r] = __builtin_amdgcn_exp2f(stt[s2][r]);
            } else {                   // diagonal: causal mask
#pragma unroll
              for (int r = 0; r < 4; ++r) {
                int key = kb + (t >> 1) * 32 + quad * 8 + (t & 1) * 4 + r;
                p[r] = (key > rowbase + col) ? 0.f
                                             : __builtin_amdgcn_exp2f(stt[s2][r]);
              }
            }
#pragma unroll
            for (int r = 0; r < 4; ++r)
              pfrag[s2][t >> 1][(t & 1) * 4 + r] = (bf16)p[r];
          }
        }
      }

      // --- PV + l-accumulation: V-frags shared across the four subtiles ---
#pragma unroll
      for (int c = 0; c < 2; ++c) {
#pragma unroll
        for (int n = 0; n < 4; ++n) {
          const int row = n * 16 + col;
          const int pc = (4 * c + quad) ^ swz_g(row);
          bf16x8 bv = *(const bf16x8*)(vc + row * 64 + pc * 8);
#pragma unroll
          for (int s2 = 0; s2 < 4; ++s2)
            if (kb < qbase + 16 * s2 + 16)
              acc[s2][n] = __builtin_amdgcn_mfma_f32_16x16x32_bf16(pfrag[s2][c], bv, acc[s2][n], 0, 0, 0);
        }
#pragma unroll
        for (int s2 = 0; s2 < 4; ++s2)
          if (kb < qbase + 16 * s2 + 16)
            acc_l[s2] = __builtin_amdgcn_mfma_f32_16x16x32_bf16(pfrag[s2][c], ones, acc_l[s2], 0, 0, 0);
      }
      __builtin_amdgcn_s_setprio(0);
    }

    __syncthreads();  // drains the async stage (vmcnt) + syncs buffer swap
  }

  // --- epilogue: write unnormalized O partial (bf16) and l partial (f32) ---
  // acc_l C-layout row (quad*4+r) == O accumulator row -> direct indexing.
  // Waves with no work write zeros -- combine sums all 4 splits (exact).
  bf16* Op = Opart + (size_t)sp * S_ * D_;
#pragma unroll
  for (int s2 = 0; s2 < 4; ++s2) {
    const int rowbase = qbase + 16 * s2;
    if (col == 0) {
#pragma unroll
      for (int r = 0; r < 4; ++r)
        lws[((size_t)sp * H_ + hh) * S_ + rowbase + quad * 4 + r] = acc_l[s2][r];
    }
#pragma unroll
    for (int n = 0; n < 4; ++n)
#pragma unroll
      for (int r = 0; r < 4; ++r)
        Op[(size_t)(rowbase + quad * 4 + r) * D_ + hh * HD_ + n * 16 + col] =
            (bf16)acc[s2][n][r];
  }
}

// ---------------- combine the four K-split partials ----------------
__global__ __launch_bounds__(256) void attn_combine(const bf16* __restrict__ Opart,
                                                    const float* __restrict__ lws,
                                                    bf16* __restrict__ outb) {
  int e = (blockIdx.x * 256 + threadIdx.x) * 8;
  int s = e >> 10;              // / D_
  int h = (e & (D_ - 1)) >> 6;  // head
  float l = 0.f;
#pragma unroll
  for (int sp = 0; sp < NSPLIT; ++sp) l += lws[((size_t)sp * H_ + h) * S_ + s];
  float inv = 1.0f / l;
  float o[8] = {};
#pragma unroll
  for (int sp = 0; sp < NSPLIT; ++sp) {
    bf16x8 a = *(const bf16x8*)(Opart + (size_t)sp * S_ * D_ + e);
#pragma unroll
    for (int j = 0; j < 8; ++j) o[j] += (float)a[j];
  }
  bf16x8 r;
#pragma unroll
  for (int j = 0; j < 8; ++j) r[j] = (bf16)(o[j] * inv);
  *(bf16x8*)(outb + e) = r;
}

// ---------------- host orchestration ----------------
extern "C" void kernel_launch(void* const* d_in, const int* in_sizes, int n_in,
                              void* d_out, int out_size, void* d_ws, size_t ws_size,
                              hipStream_t stream) {
  const float* x      = (const float*)d_in[0];
  const float* w_qkv  = (const float*)d_in[1];
  const float* b_qkv  = (const float*)d_in[2];
  const float* w_proj = (const float*)d_in[3];
  const float* b_proj = (const float*)d_in[4];
  float* out = (float*)d_out;

  bf16* xb     = (bf16*)d_ws;                       // [4096][1024]    8 MB (reused as attn)
  bf16* wqkvT  = xb + (size_t)S_ * D_;              // [3072][1024]    6 MB
  bf16* wprojT = wqkvT + (size_t)N3_ * D_;          // [1024][1024]    2 MB
  bf16* qkv    = wprojT + (size_t)D_ * D_;          // [4096][3072]   24 MB (V cols unused)
  bf16* vT     = qkv + (size_t)S_ * N3_;            // [1024][4096]    8 MB
  bf16* Opart  = vT + (size_t)D_ * S_;              // [4][4096][1024] 32 MB
  float* lws   = (float*)(Opart + (size_t)NSPLIT * S_ * D_);  // [4][16][4096] 1 MB
  bf16* attn   = xb;  // xb is dead after the QKV GEMM

  const float QSCALE = 0.125f * 1.44269504088896f;  // 1/sqrt(64) * log2(e)

  prep_kernel<<<dim3(8192), 256, 0, stream>>>(x, xb, w_qkv, wqkvT, w_proj, wprojT);
  // QKV GEMM; Q columns pre-scaled; V columns written transposed to vT
  gemm_bt<128><<<dim3(S_ / 128, N3_ / 128), 256, 0, stream>>>(
      xb, wqkvT, b_qkv, qkv, nullptr, vT, S_, N3_, D_, D_, QSCALE);
  attn_kernel<<<dim3(H_, S_ / 256, NSPLIT), 256, 0, stream>>>(qkv, vT, Opart, lws);
  attn_combine<<<dim3((S_ * D_) / 2048), 256, 0, stream>>>(Opart, lws, attn);
  // proj GEMM: 128x64 tiles -> 512 blocks (2/CU) for latency hiding
  gemm_bt<64><<<dim3(S_ / 128, D_ / 64), 256, 0, stream>>>(
      attn, wprojT, b_proj, nullptr, out, nullptr, S_, D_, D_, 0, 1.0f);
}

// Round 3
// 214.266 us; speedup vs baseline: 1.1180x; 1.1180x over previous
//
#include <hip/hip_runtime.h>
#include <hip/hip_bf16.h>
#include <math.h>

typedef __bf16 bf16;
typedef __bf16 bf16x8 __attribute__((ext_vector_type(8)));
typedef __bf16 bf16x4 __attribute__((ext_vector_type(4)));
typedef float f32x4 __attribute__((ext_vector_type(4)));

#define S_ 4096
#define D_ 1024
#define H_ 16
#define HD_ 64
#define N3_ 3072
#define NSPLIT 4

// async global->LDS 16B (m97 pattern)
typedef const __attribute__((address_space(1))) void* gas1_t;
typedef __attribute__((address_space(3))) void* las3_t;
static __device__ __forceinline__ void g2l16(const void* g, void* l) {
  __builtin_amdgcn_global_load_lds((gas1_t)g, (las3_t)l, 16, 0, 0);
}

// ---------------- fused prep: cvt x -> bf16, transpose both weights ----------------
// grid: [0,4096) cvt | [4096,7168) w_qkv transpose | [7168,8192) w_proj transpose
__global__ __launch_bounds__(256) void prep_kernel(const float* __restrict__ x,
                                                   bf16* __restrict__ xb,
                                                   const float* __restrict__ w_qkv,
                                                   bf16* __restrict__ wqkvT,
                                                   const float* __restrict__ w_proj,
                                                   bf16* __restrict__ wprojT) {
  __shared__ float t[32][33];
  const int b = blockIdx.x;
  if (b < 4096) {
    int i = (b * 256 + threadIdx.x) * 4;
    float4 v = *(const float4*)(x + i);
    bf16x4 o;
    o.x = (bf16)v.x; o.y = (bf16)v.y; o.z = (bf16)v.z; o.w = (bf16)v.w;
    *(bf16x4*)(xb + i) = o;
    return;
  }
  const float* in; bf16* outp; int ldin, bx, by;
  if (b < 7168) { int b2 = b - 4096; in = w_qkv;  outp = wqkvT;  ldin = N3_; bx = (b2 % 96) * 32; by = (b2 / 96) * 32; }
  else          { int b3 = b - 7168; in = w_proj; outp = wprojT; ldin = D_;  bx = (b3 % 32) * 32; by = (b3 / 32) * 32; }
  const int tx = threadIdx.x & 31, ty = threadIdx.x >> 5;
#pragma unroll
  for (int i = 0; i < 4; ++i)
    t[ty + i * 8][tx] = in[(size_t)(by + ty + i * 8) * ldin + bx + tx];
  __syncthreads();
#pragma unroll
  for (int i = 0; i < 4; ++i)
    outp[(size_t)(bx + ty + i * 8) * D_ + by + tx] = (bf16)t[tx][ty + i * 8];
}

// ---------------- bf16 GEMM (m97 pattern): C = A * Bt^T + bias ----------------
// 128xBN tile, BK=32, global_load_lds width-16 staging into contiguous rows.
// Columns gn < qlim get an extra fp32 scale (folds softmax scale into Q).
// If vTout != nullptr, columns gn >= 2048 are written TRANSPOSED to vTout
// (vTout[(gn-2048)*S + gm]) instead of outb -- fuses the V transpose.
template <int BN>
__global__ __launch_bounds__(256) void gemm_bt(const bf16* __restrict__ A,
                                               const bf16* __restrict__ Bt,
                                               const float* __restrict__ bias,
                                               bf16* __restrict__ outb,
                                               float* __restrict__ outf,
                                               bf16* __restrict__ vTout,
                                               int M, int N, int K,
                                               int qlim, float qscale) {
  constexpr int NT = BN / 32;  // n-tiles per wave
  __shared__ bf16 sA[128 * 32];
  __shared__ bf16 sB[BN * 32];
  const int tid = threadIdx.x;
  const int wave = tid >> 6, lane = tid & 63;
  const int col = lane & 15, quad = lane >> 4;
  const int wm = (wave & 1) * 64, wn = (wave >> 1) * (BN / 2);
  const long bm = (long)blockIdx.x * 128, bn = (long)blockIdx.y * BN;
  const int srow = tid >> 2;        // 0..63
  const int soff = (tid & 3) * 8;   // elem in 32-elem row

  f32x4 acc[4][NT] = {};

  for (int kb = 0; kb < K; kb += 32) {
    __syncthreads();
    g2l16(A + (bm + srow) * (long)K + kb + soff,      &sA[tid * 8]);
    g2l16(A + (bm + 64 + srow) * (long)K + kb + soff, &sA[2048 + tid * 8]);
#pragma unroll
    for (int i = 0; i < BN / 64; ++i)
      g2l16(Bt + (bn + i * 64 + srow) * (long)K + kb + soff, &sB[i * 2048 + tid * 8]);
    __syncthreads();

    bf16x8 af[4], bfr[NT];
#pragma unroll
    for (int t = 0; t < 4; ++t)
      af[t] = *(const bf16x8*)(&sA[(wm + t * 16 + col) * 32 + quad * 8]);
#pragma unroll
    for (int t = 0; t < NT; ++t)
      bfr[t] = *(const bf16x8*)(&sB[(wn + t * 16 + col) * 32 + quad * 8]);
#pragma unroll
    for (int mt = 0; mt < 4; ++mt)
#pragma unroll
      for (int nt = 0; nt < NT; ++nt)
        acc[mt][nt] = __builtin_amdgcn_mfma_f32_16x16x32_bf16(af[mt], bfr[nt], acc[mt][nt], 0, 0, 0);
  }

#pragma unroll
  for (int mt = 0; mt < 4; ++mt) {
#pragma unroll
    for (int nt = 0; nt < NT; ++nt) {
      long gn = bn + wn + nt * 16 + col;
      float bv = bias ? bias[gn] : 0.f;
      if (vTout && gn >= 2 * D_) {  // V column -> transposed store
        bf16x4 vv;
        long gm0 = bm + wm + mt * 16 + quad * 4;
#pragma unroll
        for (int i = 0; i < 4; ++i) vv[i] = (bf16)(acc[mt][nt][i] + bv);
        *(bf16x4*)(&vTout[(gn - 2 * D_) * (long)S_ + gm0]) = vv;
      } else {
        float sc = (gn < qlim) ? qscale : 1.0f;
#pragma unroll
        for (int i = 0; i < 4; ++i) {
          long gm = bm + wm + mt * 16 + quad * 4 + i;
          float v = (acc[mt][nt][i] + bv) * sc;
          if (outf) outf[gm * N + gn] = v;
          else      outb[gm * N + gn] = (bf16)v;
        }
      }
    }
  }
}

// ---------------- causal flash attention, 4-way exact K-split ----------------
// grid (H, 32, 4), block 256 = 4 waves; 128 q-rows/block (32/wave as two 16-row
// subtiles sharing K/V fragment reads); 64-key chunks, double-buffered
// XOR-swizzled LDS, ONE barrier per iter.
// STAGING (changed this round): global_load_lds direct (no VGPR round-trip,
// no ds_writes). LDS dst is linear (wave base + lane*16B); the XOR swizzle is
// applied to the per-lane global SOURCE address instead (m173 pattern) -- LDS
// slot (row, x) holds global 16B-chunk x ^ swz_g(row), identical content to
// the old reg-staged path, so the read side is unchanged.
// Q is pre-scaled by 0.125*log2e (QKV-GEMM epilogue) so p = exp2(s) directly.
// l is computed by MFMA against a ones B-frag (C-layout rows == O rows).
// Split sp covers a contiguous sub-range of the 2(qb+1) chunks; no-max softmax
// partials combine by PURE ADDITION in attn_combine -- exact. Empty splits
// write zero partials.
__device__ __forceinline__ int swz_g(int row) {
  return (row & 3) | ((((row >> 2) ^ (row >> 3)) & 1) << 2);
}

__global__ __launch_bounds__(256) void attn_kernel(const bf16* __restrict__ qkv,
                                                   const bf16* __restrict__ vT,
                                                   bf16* __restrict__ Opart,
                                                   float* __restrict__ lws) {
  __shared__ bf16 sK[2][64 * 64];
  __shared__ bf16 sV[2][64 * 64];
  const int hh = blockIdx.x;
  const int qb = (int)(gridDim.y - 1 - blockIdx.y);  // heavy blocks dispatch first
  const int sp = blockIdx.z;
  const int tid = threadIdx.x;
  const int wave = tid >> 6, lane = tid & 63;
  const int col = lane & 15, quad = lane >> 4;
  const int qbase = qb * 128 + wave * 32;

  // Q fragments (B-operand layout) for the two 16-row subtiles
  const bf16* qp0 = qkv + (size_t)(qbase + col) * N3_ + hh * HD_;
  bf16x8 aq[2][2];
  aq[0][0] = *(const bf16x8*)(qp0 + quad * 8);
  aq[0][1] = *(const bf16x8*)(qp0 + 32 + quad * 8);
  aq[1][0] = *(const bf16x8*)(qp0 + 16 * N3_ + quad * 8);
  aq[1][1] = *(const bf16x8*)(qp0 + 16 * N3_ + 32 + quad * 8);

  bf16x8 ones;
#pragma unroll
  for (int j = 0; j < 8; ++j) ones[j] = (bf16)1.0f;

  f32x4 acc[2][4] = {};
  f32x4 acc_l[2] = {};

  const bf16* kgbase = qkv + D_ + hh * HD_;
  const bf16* vgbase = vT + (size_t)hh * HD_ * S_;
  const int krow = (col >> 2) * 8 + (col & 3);  // permuted K row (m = col)
  const int niter = 2 * (qb + 1);
  const int base = niter >> 2, rem = niter & 3;
  const int it0 = sp * base + (sp < rem ? sp : rem);
  const int len = base + (sp < rem ? 1 : 0);
  const int it1 = it0 + len;

  // --- global_load_lds staging map: per instruction q, this thread stages
  // LDS row rq = q*32 + wave*8 + (lane>>3), slot sl = lane&7 (linear dst
  // = wave-uniform base + lane*16B). Source chunk is inverse-swizzled:
  // c_q = sl ^ swz_g(rq), so slot (row, x) holds chunk x ^ swz_g(row).
  const int lrow = lane >> 3, sl = lane & 7;
  const int row0 = wave * 8 + lrow;   // q=0: rows 0..31
  const int row1 = row0 + 32;         // q=1: rows 32..63
  const int c0 = sl ^ swz_g(row0);
  const int c1 = sl ^ swz_g(row1);
  const int dst0 = wave * 512 + lane * 8;   // bf16 elems; == wave*1KB + lane*16B
  const int dst1 = dst0 + 2048;

  if (len > 0) {
    // prologue: stage chunk it0 into buf 0
    {
      const int kb0 = it0 * 64;
      g2l16(kgbase + (size_t)(kb0 + row0) * N3_ + c0 * 8, &sK[0][dst0]);
      g2l16(kgbase + (size_t)(kb0 + row1) * N3_ + c1 * 8, &sK[0][dst1]);
      g2l16(vgbase + (size_t)row0 * S_ + kb0 + c0 * 8, &sV[0][dst0]);
      g2l16(vgbase + (size_t)row1 * S_ + kb0 + c1 * 8, &sV[0][dst1]);
    }
    __syncthreads();

    for (int j = it0; j < it1; ++j) {
      const int kb = j * 64;
      const int cur = (j - it0) & 1;
      if (j + 1 < it1) {  // stage next chunk into the other buffer (async DMA)
        const int kb2 = kb + 64;
        const int nb = cur ^ 1;
        g2l16(kgbase + (size_t)(kb2 + row0) * N3_ + c0 * 8, &sK[nb][dst0]);
        g2l16(kgbase + (size_t)(kb2 + row1) * N3_ + c1 * 8, &sK[nb][dst1]);
        g2l16(vgbase + (size_t)row0 * S_ + kb2 + c0 * 8, &sV[nb][dst0]);
        g2l16(vgbase + (size_t)row1 * S_ + kb2 + c1 * 8, &sV[nb][dst1]);
      }

      if (kb < qbase + 32) {  // wave has unmasked work in this chunk
        const bool act0 = kb < qbase + 16;
        const bf16* kc = &sK[cur][0];
        const bf16* vc = &sV[cur][0];

        // --- S^T tiles: t = (chunk c = t>>1, half h = t&1); K-frags shared ---
        f32x4 st[2][4];
        __builtin_amdgcn_s_setprio(1);
#pragma unroll
        for (int t = 0; t < 4; ++t) {
          int row = (t >> 1) * 32 + (t & 1) * 4 + krow;
          int pc = quad ^ swz_g(row);
          bf16x8 bk0 = *(const bf16x8*)(kc + row * 64 + pc * 8);
          bf16x8 bk1 = *(const bf16x8*)(kc + row * 64 + (pc ^ 4) * 8);
          if (act0) {
            f32x4 z = {};
            z = __builtin_amdgcn_mfma_f32_16x16x32_bf16(bk0, aq[0][0], z, 0, 0, 0);
            st[0][t] = __builtin_amdgcn_mfma_f32_16x16x32_bf16(bk1, aq[0][1], z, 0, 0, 0);
          }
          f32x4 z = {};
          z = __builtin_amdgcn_mfma_f32_16x16x32_bf16(bk0, aq[1][0], z, 0, 0, 0);
          st[1][t] = __builtin_amdgcn_mfma_f32_16x16x32_bf16(bk1, aq[1][1], z, 0, 0, 0);
        }
        __builtin_amdgcn_s_setprio(0);

        // --- p = exp2(s); causal mask only on diagonal chunks ---
        bf16x8 pfrag[2][2];
#pragma unroll
        for (int s2 = 0; s2 < 2; ++s2) {
          if (s2 == 0 && !act0) continue;
          const int rowbase = qbase + 16 * s2;
          float p[4][4];
          if (kb + 63 <= rowbase) {  // fully unmasked
#pragma unroll
            for (int t = 0; t < 4; ++t)
#pragma unroll
              for (int r = 0; r < 4; ++r)
                p[t][r] = __builtin_amdgcn_exp2f(st[s2][t][r]);
          } else {                   // diagonal: causal mask
#pragma unroll
            for (int t = 0; t < 4; ++t)
#pragma unroll
              for (int r = 0; r < 4; ++r) {
                int key = kb + (t >> 1) * 32 + quad * 8 + (t & 1) * 4 + r;
                p[t][r] = (key > rowbase + col)
                              ? 0.f
                              : __builtin_amdgcn_exp2f(st[s2][t][r]);
              }
          }
#pragma unroll
          for (int c = 0; c < 2; ++c)
#pragma unroll
            for (int j2 = 0; j2 < 4; ++j2) {
              pfrag[s2][c][j2]     = (bf16)p[2 * c][j2];
              pfrag[s2][c][j2 + 4] = (bf16)p[2 * c + 1][j2];
            }
        }

        // --- PV + l-accumulation: V-frags shared across subtiles ---
        __builtin_amdgcn_s_setprio(1);
#pragma unroll
        for (int c = 0; c < 2; ++c) {
#pragma unroll
          for (int n = 0; n < 4; ++n) {
            int row = n * 16 + col;
            int pc = (4 * c + quad) ^ swz_g(row);
            bf16x8 bv = *(const bf16x8*)(vc + row * 64 + pc * 8);
            if (act0)
              acc[0][n] = __builtin_amdgcn_mfma_f32_16x16x32_bf16(pfrag[0][c], bv, acc[0][n], 0, 0, 0);
            acc[1][n] = __builtin_amdgcn_mfma_f32_16x16x32_bf16(pfrag[1][c], bv, acc[1][n], 0, 0, 0);
          }
          if (act0)
            acc_l[0] = __builtin_amdgcn_mfma_f32_16x16x32_bf16(pfrag[0][c], ones, acc_l[0], 0, 0, 0);
          acc_l[1] = __builtin_amdgcn_mfma_f32_16x16x32_bf16(pfrag[1][c], ones, acc_l[1], 0, 0, 0);
        }
        __builtin_amdgcn_s_setprio(0);
      }

      __syncthreads();  // drains staging DMA (vmcnt) + synchronizes buffer swap
    }
  }

  // --- epilogue: write unnormalized O partial (bf16) and l partial (f32) ---
  // acc_l C-layout row (quad*4+r) == O accumulator row -> direct indexing.
  // Runs for empty splits too (writes zeros -- combine sums all 4 partials).
  bf16* Op = Opart + (size_t)sp * S_ * D_;
#pragma unroll
  for (int s2 = 0; s2 < 2; ++s2) {
    const int rowbase = qbase + 16 * s2;
    if (col == 0) {
#pragma unroll
      for (int r = 0; r < 4; ++r)
        lws[((size_t)sp * H_ + hh) * S_ + rowbase + quad * 4 + r] = acc_l[s2][r];
    }
#pragma unroll
    for (int n = 0; n < 4; ++n)
#pragma unroll
      for (int r = 0; r < 4; ++r)
        Op[(size_t)(rowbase + quad * 4 + r) * D_ + hh * HD_ + n * 16 + col] =
            (bf16)acc[s2][n][r];
  }
}

// ---------------- combine the four K-split partials ----------------
__global__ __launch_bounds__(256) void attn_combine(const bf16* __restrict__ Opart,
                                                    const float* __restrict__ lws,
                                                    bf16* __restrict__ outb) {
  int e = (blockIdx.x * 256 + threadIdx.x) * 8;
  int s = e >> 10;              // / D_
  int h = (e & (D_ - 1)) >> 6;  // head
  float l = 0.f;
#pragma unroll
  for (int sp = 0; sp < NSPLIT; ++sp) l += lws[((size_t)sp * H_ + h) * S_ + s];
  float inv = 1.0f / l;
  float o[8] = {};
#pragma unroll
  for (int sp = 0; sp < NSPLIT; ++sp) {
    bf16x8 a = *(const bf16x8*)(Opart + (size_t)sp * S_ * D_ + e);
#pragma unroll
    for (int j = 0; j < 8; ++j) o[j] += (float)a[j];
  }
  bf16x8 r;
#pragma unroll
  for (int j = 0; j < 8; ++j) r[j] = (bf16)(o[j] * inv);
  *(bf16x8*)(outb + e) = r;
}

// ---------------- host orchestration ----------------
extern "C" void kernel_launch(void* const* d_in, const int* in_sizes, int n_in,
                              void* d_out, int out_size, void* d_ws, size_t ws_size,
                              hipStream_t stream) {
  const float* x      = (const float*)d_in[0];
  const float* w_qkv  = (const float*)d_in[1];
  const float* b_qkv  = (const float*)d_in[2];
  const float* w_proj = (const float*)d_in[3];
  const float* b_proj = (const float*)d_in[4];
  float* out = (float*)d_out;

  bf16* xb     = (bf16*)d_ws;                       // [4096][1024]    8 MB (reused as attn)
  bf16* wqkvT  = xb + (size_t)S_ * D_;              // [3072][1024]    6 MB
  bf16* wprojT = wqkvT + (size_t)N3_ * D_;          // [1024][1024]    2 MB
  bf16* qkv    = wprojT + (size_t)D_ * D_;          // [4096][3072]   24 MB (V cols unused)
  bf16* vT     = qkv + (size_t)S_ * N3_;            // [1024][4096]    8 MB
  bf16* Opart  = vT + (size_t)D_ * S_;              // [4][4096][1024] 32 MB
  float* lws   = (float*)(Opart + (size_t)NSPLIT * S_ * D_);  // [4][16][4096] 1 MB
  bf16* attn   = xb;  // xb is dead after the QKV GEMM

  const float QSCALE = 0.125f * 1.44269504088896f;  // 1/sqrt(64) * log2(e)

  prep_kernel<<<dim3(8192), 256, 0, stream>>>(x, xb, w_qkv, wqkvT, w_proj, wprojT);
  // QKV GEMM; Q columns pre-scaled; V columns written transposed to vT
  gemm_bt<128><<<dim3(S_ / 128, N3_ / 128), 256, 0, stream>>>(
      xb, wqkvT, b_qkv, qkv, nullptr, vT, S_, N3_, D_, D_, QSCALE);
  attn_kernel<<<dim3(H_, S_ / 128, NSPLIT), 256, 0, stream>>>(qkv, vT, Opart, lws);
  attn_combine<<<dim3((S_ * D_) / 2048), 256, 0, stream>>>(Opart, lws, attn);
  // proj GEMM: 128x64 tiles -> 512 blocks (2/CU) for latency hiding
  gemm_bt<64><<<dim3(S_ / 128, D_ / 64), 256, 0, stream>>>(
      attn, wprojT, b_proj, nullptr, out, nullptr, S_, D_, D_, 0, 1.0f);
}